// Round 15
// baseline (119.461 us; speedup 1.0000x reference)
//
#include <hip/hip_runtime.h>

// B=4, N=1024, E=1024, H=16, D=64.  bf16 MFMA (16x16x32), fp32 accum.
// Raw-reshape: per batch-head bh, Q/K/V slab = flat [bh*65536, +65536) viewed [1024 n][64 d].
// GEMMs: 128x128 tile, 768/256 blocks, 2-buffer LDS, counted vmcnt(4) (T4), granule-XOR
// swizzle (T2), bijective XCD swizzle. Q PRE-SCALED by 0.125*log2(e) -> exp2 softmax.
// transpose_v builds V^T per head.
// Attention (r15): UN-PAIRED — 2048 single-q-tile blocks, 4-wave split-K, one merge.
// Descending-qt dispatch (LPT): long blocks (qt=31) launch first, short blocks pack the
// tail; CUs re-fill dynamically -> sustained residency at the VGPR cap instead of the
// paired 2-pass structure's static 16 waves/CU. XCD remap keeps each bh's slab on one L2.

typedef __bf16 bf16x8 __attribute__((ext_vector_type(8)));
typedef float f32x4 __attribute__((ext_vector_type(4)));

#define QSCALE 0.18033688011112042f   // 0.125 * log2(e)
#define DEFER_THR 11.0f               // log2 domain; P bounded by 2^11

__device__ __forceinline__ unsigned short f2bf(float f) {
    unsigned u = __float_as_uint(f);
    u += 0x7fffu + ((u >> 16) & 1u);   // round-to-nearest-even
    return (unsigned short)(u >> 16);
}

__device__ __forceinline__ unsigned cvtpk_bf16(float lo, float hi) {
    unsigned r;
    asm("v_cvt_pk_bf16_f32 %0, %1, %2" : "=v"(r) : "v"(lo), "v"(hi));
    return r;
}

union FragU { uint4 u; bf16x8 v; };

__device__ __forceinline__ bf16x8 ld_frag(const unsigned short* p) {
    FragU x; x.u = *(const uint4*)p; return x.v;
}

__device__ __forceinline__ void gload_lds16(const void* g, void* l) {
    __builtin_amdgcn_global_load_lds(
        (const __attribute__((address_space(1))) void*)g,
        (__attribute__((address_space(3))) void*)l, 16, 0, 0);
}

// ---------------- fused prep: x->bf16 + both weight transposes (one launch) ----------------
__global__ __launch_bounds__(256) void prep(
    const float* __restrict__ x,    unsigned short* __restrict__ xb,
    const float* __restrict__ Wqkv, unsigned short* __restrict__ wqkvT,
    const float* __restrict__ Wfc,  unsigned short* __restrict__ wfcT)
{
    __shared__ float tile[32][33];
    int bid = blockIdx.x;
    int tx = threadIdx.x & 31, ty = threadIdx.x >> 5;   // (32,8)
    if (bid < 3072) {
        int c0 = (bid % 96) * 32, r0 = (bid / 96) * 32;
        for (int i = ty; i < 32; i += 8)
            tile[i][tx] = Wqkv[(r0 + i) * 3072 + c0 + tx];
        __syncthreads();
        for (int i = ty; i < 32; i += 8)
            wqkvT[(long)(c0 + i) * 1024 + r0 + tx] = f2bf(tile[tx][i]);
    } else if (bid < 4096) {
        int b2 = bid - 3072;
        int c0 = (b2 % 32) * 32, r0 = (b2 / 32) * 32;
        for (int i = ty; i < 32; i += 8)
            tile[i][tx] = Wfc[(r0 + i) * 1024 + c0 + tx];
        __syncthreads();
        for (int i = ty; i < 32; i += 8)
            wfcT[(long)(c0 + i) * 1024 + r0 + tx] = f2bf(tile[tx][i]);
    } else {
        const int n4 = 1 << 20;
        for (int i = (bid - 4096) * 256 + threadIdx.x; i < n4; i += 1024 * 256) {
            float4 f = ((const float4*)x)[i];
            unsigned a = (unsigned)f2bf(f.x) | ((unsigned)f2bf(f.y) << 16);
            unsigned b = (unsigned)f2bf(f.z) | ((unsigned)f2bf(f.w) << 16);
            ((uint2*)xb)[i] = make_uint2(a, b);
        }
    }
}

// ---------------- per-head V transpose: [1024 n][64 d] -> [64 d][1024 n] ----------------
__global__ void transpose_v(const unsigned short* __restrict__ v,
                            unsigned short* __restrict__ vt) {
    __shared__ unsigned short tile[32][33];
    int bh = blockIdx.z;
    int n0 = blockIdx.x * 32, d0 = blockIdx.y * 32;
    const unsigned short* src = v + (long)bh * 65536;
    unsigned short* dst = vt + (long)bh * 65536;
    for (int i = threadIdx.y; i < 32; i += 8)
        tile[i][threadIdx.x] = src[(n0 + i) * 64 + d0 + threadIdx.x];
    __syncthreads();
    for (int i = threadIdx.y; i < 32; i += 8)
        dst[(d0 + i) * 1024 + n0 + threadIdx.x] = tile[threadIdx.x][i];
}

// ---------------- bf16 GEMM, 128x128 tile, 2-buffer counted-vmcnt + granule swizzle ----------------
template <int MODE>
__global__ __launch_bounds__(256) void gemm128(
    const unsigned short* __restrict__ A,    // [M,1024] bf16
    const unsigned short* __restrict__ Bt,   // [N,1024] bf16
    const float* __restrict__ bias,          // [N]
    unsigned short* __restrict__ qb,
    unsigned short* __restrict__ kb,
    unsigned short* __restrict__ vb,
    float* __restrict__ outf)
{
    __shared__ unsigned short As[2][4096];   // [128 rows][32 k], rows = 64B = 4 granules
    __shared__ unsigned short Bs[2][4096];
    int t = threadIdx.x, lane = t & 63, w = t >> 6;
    int wm = w >> 1, wn = w & 1;
    int lrow = lane >> 4, lcol = lane & 15;

    const int NX  = (MODE == 0) ? 24 : 8;
    const int CPX = (MODE == 0) ? 96 : 32;
    int id = blockIdx.x;
    int idp = (id & 7) * CPX + (id >> 3);    // bijective XCD swizzle (grid % 8 == 0)
    int tn0 = (idp % NX) * 128, tm0 = (idp / NX) * 128;

    int seg0 = w * 1024;
    int seg1 = (w + 4) * 1024;
    int off0 = seg0 + lane * 16, off1 = seg1 + lane * 16;
    int r0 = off0 >> 6, g0 = ((((off0 >> 4) & 3) ^ ((r0 >> 1) & 3)) << 4);
    int r1 = off1 >> 6, g1 = ((((off1 >> 4) & 3) ^ ((r1 >> 1) & 3)) << 4);

    const char* gA = (const char*)A;
    const char* gB = (const char*)Bt;

    int aoff[4], boff[4];
    #pragma unroll
    for (int mi = 0; mi < 4; ++mi) {
        int row = wm * 64 + mi * 16 + lcol;
        aoff[mi] = row * 32 + ((lrow ^ ((row >> 1) & 3)) << 3);
    }
    #pragma unroll
    for (int ni = 0; ni < 4; ++ni) {
        int row = wn * 64 + ni * 16 + lcol;
        boff[ni] = row * 32 + ((lrow ^ ((row >> 1) & 3)) << 3);
    }

    f32x4 acc[4][4] = {};

    auto STAGE = [&](int buf, int kt) {
        long kby = (long)kt * 2;
        gload_lds16(gA + (long)(tm0 + r0) * 2048 + kby + g0, (char*)&As[buf][0] + seg0);
        gload_lds16(gA + (long)(tm0 + r1) * 2048 + kby + g1, (char*)&As[buf][0] + seg1);
        gload_lds16(gB + (long)(tn0 + r0) * 2048 + kby + g0, (char*)&Bs[buf][0] + seg0);
        gload_lds16(gB + (long)(tn0 + r1) * 2048 + kby + g1, (char*)&Bs[buf][0] + seg1);
    };

    STAGE(0, 0);
    STAGE(1, 32);

    for (int tt = 0; tt < 32; ++tt) {
        if (tt < 31) asm volatile("s_waitcnt vmcnt(4)" ::: "memory");
        else         asm volatile("s_waitcnt vmcnt(0)" ::: "memory");
        __builtin_amdgcn_s_barrier();          // tile tt landed for all waves

        int cur = tt & 1;
        bf16x8 af[4], bfr[4];
        #pragma unroll
        for (int mi = 0; mi < 4; ++mi) af[mi] = ld_frag(&As[cur][aoff[mi]]);
        #pragma unroll
        for (int ni = 0; ni < 4; ++ni) bfr[ni] = ld_frag(&Bs[cur][boff[ni]]);
        #pragma unroll
        for (int mi = 0; mi < 4; ++mi)
            #pragma unroll
            for (int ni = 0; ni < 4; ++ni)
                acc[mi][ni] = __builtin_amdgcn_mfma_f32_16x16x32_bf16(af[mi], bfr[ni], acc[mi][ni], 0, 0, 0);

        __builtin_amdgcn_s_barrier();          // all reads of buf[cur] done
        if (tt + 2 < 32) STAGE(cur, (tt + 2) * 32);
    }

    #pragma unroll
    for (int mi = 0; mi < 4; ++mi) {
        int gr0 = tm0 + wm * 64 + mi * 16 + lrow * 4;
        #pragma unroll
        for (int ni = 0; ni < 4; ++ni) {
            int gc = tn0 + wn * 64 + ni * 16 + lcol;
            float bv = bias[gc];
            if (MODE == 0) {
                int sec = gc >> 10, ei = gc & 1023;
                unsigned short* dst = sec == 0 ? qb : (sec == 1 ? kb : vb);
                if (sec == 0) {
                    #pragma unroll
                    for (int r = 0; r < 4; ++r)
                        dst[(long)(gr0 + r) * 1024 + ei] = f2bf((acc[mi][ni][r] + bv) * QSCALE);
                } else {
                    #pragma unroll
                    for (int r = 0; r < 4; ++r)
                        dst[(long)(gr0 + r) * 1024 + ei] = f2bf(acc[mi][ni][r] + bv);
                }
            } else {
                #pragma unroll
                for (int r = 0; r < 4; ++r)
                    outf[(long)(gr0 + r) * 1024 + gc] = acc[mi][ni][r] + bv;
            }
        }
    }
}

// ---------------- flash attention: un-paired, LPT dispatch, 4-wave split-K ----------------
// id -> (xcd = id&7, s = id>>3): qt = 31 - (s>>3) [descending: long blocks first],
// bh = xcd + 8*(s&7) [bh pinned to XCD bh&7 -> slab L2-resident].
__global__ __launch_bounds__(256) void attn(
    const unsigned short* __restrict__ qbuf,
    const unsigned short* __restrict__ kbuf,
    const unsigned short* __restrict__ vtbuf,
    unsigned short* __restrict__ obuf)
{
    // smem (17,920 B), phase-aliased:
    //   loop phase : Ps [4][32][40] ushort (10,240 B)
    //   merge phase: accH [4][32][68] f16 (17,408 B) + mS [4][32] f32 (512 B)
    __shared__ char smem[17920] __attribute__((aligned(16)));
    unsigned short (*Ps)[32][40] = (unsigned short (*)[32][40])smem;
    _Float16* accH = (_Float16*)smem;                 // [4][32][68]
    float* mS = (float*)(smem + 17408);               // [4][32]

    int id = blockIdx.x;
    int xcd = id & 7, s_ = id >> 3;
    int qt = 31 - (s_ >> 3);
    int bh = xcd + 8 * (s_ & 7);

    const unsigned short* Q  = qbuf + (long)bh * 65536;
    const unsigned short* Kp = kbuf + (long)bh * 65536;
    const unsigned short* VT = vtbuf + (long)bh * 65536;   // [64 d][1024 n]
    unsigned short* O = obuf + (long)bh * 65536;
    int t = threadIdx.x, lane = t & 63, w = t >> 6;
    int lrow = lane >> 4, lcol = lane & 15;
    const float NEG = -__builtin_inff();

    int qbase = qt * 32;
    int T = qt + 1;

    bf16x8 qf[2][2];
    #pragma unroll
    for (int qg = 0; qg < 2; ++qg)
        #pragma unroll
        for (int kc = 0; kc < 2; ++kc)
            qf[qg][kc] = ld_frag(Q + (long)(qbase + qg * 16 + lcol) * 64 + kc * 32 + lrow * 8);

    f32x4 acc[2][4] = {};
    float m_i[2] = {NEG, NEG};
    float lsum[2][2] = {{0.f, 0.f}, {0.f, 0.f}};

    if (w < T) {
        int kt = w * 32;
        bf16x8 kf[2][2];
        #pragma unroll
        for (int kg = 0; kg < 2; ++kg)
            #pragma unroll
            for (int kc = 0; kc < 2; ++kc)
                kf[kg][kc] = ld_frag(Kp + (long)(kt + kg * 16 + lcol) * 64 + kc * 32 + lrow * 8);

        // prologue: S for first owned tile
        f32x4 s[2][2] = {};
        #pragma unroll
        for (int kg = 0; kg < 2; ++kg)
            #pragma unroll
            for (int kc = 0; kc < 2; ++kc) {
                s[0][kg] = __builtin_amdgcn_mfma_f32_16x16x32_bf16(kf[kg][kc], qf[0][kc], s[0][kg], 0, 0, 0);
                s[1][kg] = __builtin_amdgcn_mfma_f32_16x16x32_bf16(kf[kg][kc], qf[1][kc], s[1][kg], 0, 0, 0);
            }

        for (;;) {
            int ktn = kt + 128;
            bool more = ktn < T * 32;
            if (more) {
                #pragma unroll
                for (int kg = 0; kg < 2; ++kg)
                    #pragma unroll
                    for (int kc = 0; kc < 2; ++kc)
                        kf[kg][kc] = ld_frag(Kp + (long)(ktn + kg * 16 + lcol) * 64 + kc * 32 + lrow * 8);
            }
            bf16x8 vf[4];
            #pragma unroll
            for (int dg = 0; dg < 4; ++dg)
                vf[dg] = ld_frag(VT + (long)(dg * 16 + lcol) * 1024 + kt + lrow * 8);

            // --- softmax on S(t) ---
            bool diag = (kt == qbase);
            if (diag) {
                #pragma unroll
                for (int qg = 0; qg < 2; ++qg)
                    #pragma unroll
                    for (int kg = 0; kg < 2; ++kg)
                        #pragma unroll
                        for (int r = 0; r < 4; ++r)
                            if (kg * 16 + lrow * 4 + r > qg * 16 + lcol)
                                s[qg][kg][r] = NEG;
            }
            float lmax[2];
            #pragma unroll
            for (int qg = 0; qg < 2; ++qg) {
                float a0 = fmaxf(s[qg][0][0], s[qg][0][1]), a1 = fmaxf(s[qg][0][2], s[qg][0][3]);
                float a2 = fmaxf(s[qg][1][0], s[qg][1][1]), a3 = fmaxf(s[qg][1][2], s[qg][1][3]);
                lmax[qg] = fmaxf(fmaxf(a0, a1), fmaxf(a2, a3));
            }
            bool ok = (lmax[0] <= m_i[0] + DEFER_THR) && (lmax[1] <= m_i[1] + DEFER_THR);
            if (!__all(ok)) {
                #pragma unroll
                for (int qg = 0; qg < 2; ++qg) {
                    float mx = fmaxf(lmax[qg], __shfl_xor(lmax[qg], 16));
                    mx = fmaxf(mx, __shfl_xor(mx, 32));
                    float mnew = fmaxf(m_i[qg], mx);
                    float alpha = exp2f(m_i[qg] - mnew);
                    m_i[qg] = mnew;
                    lsum[qg][0] *= alpha;
                    lsum[qg][1] *= alpha;
                    #pragma unroll
                    for (int dg = 0; dg < 4; ++dg)
                        #pragma unroll
                        for (int r = 0; r < 4; ++r)
                            acc[qg][dg][r] *= alpha;
                }
            }
            #pragma unroll
            for (int qg = 0; qg < 2; ++qg) {
                float p[8];
                #pragma unroll
                for (int kg = 0; kg < 2; ++kg)
                    #pragma unroll
                    for (int r = 0; r < 4; ++r)
                        p[kg * 4 + r] = exp2f(s[qg][kg][r] - m_i[qg]);
                lsum[qg][0] += (p[0] + p[1]) + (p[2] + p[3]);
                lsum[qg][1] += (p[4] + p[5]) + (p[6] + p[7]);
                unsigned u0 = cvtpk_bf16(p[0], p[1]);
                unsigned u1 = cvtpk_bf16(p[2], p[3]);
                unsigned u2 = cvtpk_bf16(p[4], p[5]);
                unsigned u3 = cvtpk_bf16(p[6], p[7]);
                *(uint2*)&Ps[w][qg * 16 + lcol][lrow * 4]      = make_uint2(u0, u1);
                *(uint2*)&Ps[w][qg * 16 + lcol][16 + lrow * 4] = make_uint2(u2, u3);
            }

            bf16x8 pb[2];
            pb[0] = ld_frag(&Ps[w][lcol][lrow * 8]);
            pb[1] = ld_frag(&Ps[w][16 + lcol][lrow * 8]);

            __builtin_amdgcn_s_setprio(1);
            // QK(t+1) first: latency hides under PV + next softmax
            if (more) {
                #pragma unroll
                for (int qg = 0; qg < 2; ++qg)
                    #pragma unroll
                    for (int kg = 0; kg < 2; ++kg)
                        s[qg][kg] = (f32x4){0.f, 0.f, 0.f, 0.f};
                #pragma unroll
                for (int kg = 0; kg < 2; ++kg)
                    #pragma unroll
                    for (int kc = 0; kc < 2; ++kc) {
                        s[0][kg] = __builtin_amdgcn_mfma_f32_16x16x32_bf16(kf[kg][kc], qf[0][kc], s[0][kg], 0, 0, 0);
                        s[1][kg] = __builtin_amdgcn_mfma_f32_16x16x32_bf16(kf[kg][kc], qf[1][kc], s[1][kg], 0, 0, 0);
                    }
            }
            #pragma unroll
            for (int dg = 0; dg < 4; ++dg) {
                acc[0][dg] = __builtin_amdgcn_mfma_f32_16x16x32_bf16(vf[dg], pb[0], acc[0][dg], 0, 0, 0);
                acc[1][dg] = __builtin_amdgcn_mfma_f32_16x16x32_bf16(vf[dg], pb[1], acc[1][dg], 0, 0, 0);
            }
            __builtin_amdgcn_s_setprio(0);

            if (!more) break;
            kt = ktn;
        }
    }

    // --- merge 4 wave-partials through LDS (f16 l-normalized) ---
    __syncthreads();
    #pragma unroll
    for (int qg = 0; qg < 2; ++qg) {
        int q = qg * 16 + lcol;
        float lr = lsum[qg][0] + lsum[qg][1];
        lr += __shfl_xor(lr, 16);
        lr += __shfl_xor(lr, 32);
        float mprime, inv;
        if (lr > 0.f) { mprime = m_i[qg] + log2f(lr); inv = 1.f / lr; }
        else          { mprime = NEG; inv = 0.f; }
        if (lrow == 0) mS[w * 32 + q] = mprime;
        #pragma unroll
        for (int dg = 0; dg < 4; ++dg) {
            _Float16 a0 = (_Float16)(acc[qg][dg][0] * inv);
            _Float16 a1 = (_Float16)(acc[qg][dg][1] * inv);
            _Float16 a2 = (_Float16)(acc[qg][dg][2] * inv);
            _Float16 a3 = (_Float16)(acc[qg][dg][3] * inv);
            _Float16* dst = &accH[(w * 32 + q) * 68 + dg * 16 + lrow * 4];
            dst[0] = a0; dst[1] = a1; dst[2] = a2; dst[3] = a3;
        }
    }
    __syncthreads();

    {
        int qq = t >> 3, d0 = (t & 7) * 8;
        float m0 = mS[qq], m1 = mS[32 + qq], m2 = mS[64 + qq], m3 = mS[96 + qq];
        float M = fmaxf(fmaxf(m0, m1), fmaxf(m2, m3));
        float e0 = exp2f(m0 - M), e1 = exp2f(m1 - M), e2 = exp2f(m2 - M), e3 = exp2f(m3 - M);
        float inv = 1.f / (e0 + e1 + e2 + e3);
        const _Float16* a0 = &accH[qq * 68 + d0];
        const _Float16* a1 = &accH[(32 + qq) * 68 + d0];
        const _Float16* a2 = &accH[(64 + qq) * 68 + d0];
        const _Float16* a3 = &accH[(96 + qq) * 68 + d0];
        unsigned short h[8];
        #pragma unroll
        for (int jj = 0; jj < 8; ++jj)
            h[jj] = f2bf((e0 * (float)a0[jj] + e1 * (float)a1[jj] +
                          e2 * (float)a2[jj] + e3 * (float)a3[jj]) * inv);
        uint4 pk;
        pk.x = (unsigned)h[0] | ((unsigned)h[1] << 16);
        pk.y = (unsigned)h[2] | ((unsigned)h[3] << 16);
        pk.z = (unsigned)h[4] | ((unsigned)h[5] << 16);
        pk.w = (unsigned)h[6] | ((unsigned)h[7] << 16);
        *(uint4*)&O[(long)(qbase + qq) * 64 + d0] = pk;
    }
}

extern "C" void kernel_launch(void* const* d_in, const int* in_sizes, int n_in,
                              void* d_out, int out_size, void* d_ws, size_t ws_size,
                              hipStream_t stream) {
    const float* x    = (const float*)d_in[0];
    const float* Wqkv = (const float*)d_in[1];
    const float* bqkv = (const float*)d_in[2];
    const float* Wfc  = (const float*)d_in[3];
    const float* bfc  = (const float*)d_in[4];
    float* out = (float*)d_out;

    unsigned short* ws    = (unsigned short*)d_ws;
    unsigned short* xb    = ws;                    // 4M elems; dead after gemm<0>
    unsigned short* wqkvT = xb + (4u << 20);       // 3M
    unsigned short* wfcT  = wqkvT + (3u << 20);    // 1M
    unsigned short* qb    = wfcT + (1u << 20);     // 4M
    unsigned short* kb    = qb + (4u << 20);       // 4M
    unsigned short* vb    = kb + (4u << 20);       // 4M; dead after transpose_v
    unsigned short* vbT   = xb;                    // reuse xb
    unsigned short* ob    = vb;                    // reuse vb
    // total ws: 40 MB

    prep<<<dim3(5120), dim3(256), 0, stream>>>(x, xb, Wqkv, wqkvT, Wfc, wfcT);
    gemm128<0><<<dim3(768), dim3(256), 0, stream>>>(xb, wqkvT, bqkv, qb, kb, vb, nullptr);
    transpose_v<<<dim3(32, 2, 64), dim3(32, 8), 0, stream>>>(vb, vbT);
    attn<<<dim3(2048), dim3(256), 0, stream>>>(qb, kb, vbT, ob);
    gemm128<1><<<dim3(256), dim3(256), 0, stream>>>(ob, wfcT, bfc, nullptr, nullptr, nullptr, out);
}

// Round 16
// 111.440 us; speedup vs baseline: 1.0720x; 1.0720x over previous
//
#include <hip/hip_runtime.h>

// B=4, N=1024, E=1024, H=16, D=64.  bf16 MFMA (16x16x32), fp32 accum.
// Raw-reshape: per batch-head bh, Q/K/V slab = flat [bh*65536, +65536) viewed [1024 n][64 d].
// GEMMs: 128x128 tile, 2-buffer global_load_lds prefetch (r12 variant — best measured).
// Q PRE-SCALED by 0.125*log2(e) -> exp2 softmax. transpose_v builds V^T per head.
// Attention (r16, m214-style): block = 4 waves x 32 q-rows (128-row panel); all waves walk
// the SAME K sequence; K[64k][64d] and V^T[64d][64k] tiles staged ONCE per block into
// double-buffered LDS (global_load_lds, counted vmcnt(4), r13-proven barrier pattern);
// fragments via XOR-swizzled ds_read_b128 (slot = g ^ (row&7), source pre-swizzled with
// the same involution — rule #21). No split-K, NO merge phase: each wave owns its 32 rows.
// LPT dispatch (long panels first, 512 blocks = 2/CU re-fill) + XCD pinning.

typedef __bf16 bf16x8 __attribute__((ext_vector_type(8)));
typedef float f32x4 __attribute__((ext_vector_type(4)));

#define QSCALE 0.18033688011112042f   // 0.125 * log2(e)
#define DEFER_THR 11.0f               // log2 domain; P bounded by 2^11

__device__ __forceinline__ unsigned short f2bf(float f) {
    unsigned u = __float_as_uint(f);
    u += 0x7fffu + ((u >> 16) & 1u);   // round-to-nearest-even
    return (unsigned short)(u >> 16);
}

__device__ __forceinline__ unsigned cvtpk_bf16(float lo, float hi) {
    unsigned r;
    asm("v_cvt_pk_bf16_f32 %0, %1, %2" : "=v"(r) : "v"(lo), "v"(hi));
    return r;
}

union FragU { uint4 u; bf16x8 v; };

__device__ __forceinline__ bf16x8 ld_frag(const unsigned short* p) {
    FragU x; x.u = *(const uint4*)p; return x.v;
}

__device__ __forceinline__ void gload_lds16(const void* g, void* l) {
    __builtin_amdgcn_global_load_lds(
        (const __attribute__((address_space(1))) void*)g,
        (__attribute__((address_space(3))) void*)l, 16, 0, 0);
}

// ---------------- fused prep: x->bf16 + both weight transposes (one launch) ----------------
__global__ __launch_bounds__(256) void prep(
    const float* __restrict__ x,    unsigned short* __restrict__ xb,
    const float* __restrict__ Wqkv, unsigned short* __restrict__ wqkvT,
    const float* __restrict__ Wfc,  unsigned short* __restrict__ wfcT)
{
    __shared__ float tile[32][33];
    int bid = blockIdx.x;
    int tx = threadIdx.x & 31, ty = threadIdx.x >> 5;   // (32,8)
    if (bid < 3072) {
        int c0 = (bid % 96) * 32, r0 = (bid / 96) * 32;
        for (int i = ty; i < 32; i += 8)
            tile[i][tx] = Wqkv[(r0 + i) * 3072 + c0 + tx];
        __syncthreads();
        for (int i = ty; i < 32; i += 8)
            wqkvT[(long)(c0 + i) * 1024 + r0 + tx] = f2bf(tile[tx][i]);
    } else if (bid < 4096) {
        int b2 = bid - 3072;
        int c0 = (b2 % 32) * 32, r0 = (b2 / 32) * 32;
        for (int i = ty; i < 32; i += 8)
            tile[i][tx] = Wfc[(r0 + i) * 1024 + c0 + tx];
        __syncthreads();
        for (int i = ty; i < 32; i += 8)
            wfcT[(long)(c0 + i) * 1024 + r0 + tx] = f2bf(tile[tx][i]);
    } else {
        const int n4 = 1 << 20;
        for (int i = (bid - 4096) * 256 + threadIdx.x; i < n4; i += 1024 * 256) {
            float4 f = ((const float4*)x)[i];
            unsigned a = (unsigned)f2bf(f.x) | ((unsigned)f2bf(f.y) << 16);
            unsigned b = (unsigned)f2bf(f.z) | ((unsigned)f2bf(f.w) << 16);
            ((uint2*)xb)[i] = make_uint2(a, b);
        }
    }
}

// ---------------- per-head V transpose: [1024 n][64 d] -> [64 d][1024 n] ----------------
__global__ void transpose_v(const unsigned short* __restrict__ v,
                            unsigned short* __restrict__ vt) {
    __shared__ unsigned short tile[32][33];
    int bh = blockIdx.z;
    int n0 = blockIdx.x * 32, d0 = blockIdx.y * 32;
    const unsigned short* src = v + (long)bh * 65536;
    unsigned short* dst = vt + (long)bh * 65536;
    for (int i = threadIdx.y; i < 32; i += 8)
        tile[i][threadIdx.x] = src[(n0 + i) * 64 + d0 + threadIdx.x];
    __syncthreads();
    for (int i = threadIdx.y; i < 32; i += 8)
        dst[(d0 + i) * 1024 + n0 + threadIdx.x] = tile[threadIdx.x][i];
}

// ---------------- bf16 GEMM, 128x128 tile, double-buffered global_load_lds (r12) ----------------
template <int MODE>
__global__ __launch_bounds__(256) void gemm128(
    const unsigned short* __restrict__ A,    // [M,1024] bf16
    const unsigned short* __restrict__ Bt,   // [N,1024] bf16
    const float* __restrict__ bias,          // [N]
    unsigned short* __restrict__ qb,
    unsigned short* __restrict__ kb,
    unsigned short* __restrict__ vb,
    float* __restrict__ outf)
{
    const int K = 1024;
    __shared__ unsigned short As[2][4096];
    __shared__ unsigned short Bs[2][4096];
    int t = threadIdx.x, lane = t & 63, w = t >> 6;
    int wm = w >> 1, wn = w & 1;
    int lrow = lane >> 4, lcol = lane & 15;

    const int NX  = (MODE == 0) ? 24 : 8;
    const int CPX = (MODE == 0) ? 96 : 32;
    int id = blockIdx.x;
    int idp = (id & 7) * CPX + (id >> 3);    // bijective (grid % 8 == 0)
    int tn0 = (idp % NX) * 128, tm0 = (idp / NX) * 128;

    int seg0 = w * 1024;
    int seg1 = (w + 4) * 1024;
    int off0 = seg0 + lane * 16, off1 = seg1 + lane * 16;
    int r0 = off0 >> 6, cb0 = off0 & 63;
    int r1 = off1 >> 6, cb1 = off1 & 63;

    const char* gA = (const char*)A;
    const char* gB = (const char*)Bt;

    f32x4 acc[4][4] = {};

    auto STAGE = [&](int buf, int kt) {
        long kby = (long)kt * 2;
        gload_lds16(gA + (long)(tm0 + r0) * 2048 + kby + cb0, (char*)&As[buf][0] + seg0);
        gload_lds16(gA + (long)(tm0 + r1) * 2048 + kby + cb1, (char*)&As[buf][0] + seg1);
        gload_lds16(gB + (long)(tn0 + r0) * 2048 + kby + cb0, (char*)&Bs[buf][0] + seg0);
        gload_lds16(gB + (long)(tn0 + r1) * 2048 + kby + cb1, (char*)&Bs[buf][0] + seg1);
    };

    STAGE(0, 0);
    asm volatile("s_waitcnt vmcnt(0)");
    __syncthreads();

    int cur = 0;
    for (int kt = 0; kt < K; kt += 32) {
        if (kt + 32 < K) STAGE(cur ^ 1, kt + 32);

        bf16x8 af[4], bfr[4];
        #pragma unroll
        for (int mi = 0; mi < 4; ++mi)
            af[mi] = ld_frag(&As[cur][0] + (wm * 64 + mi * 16 + lcol) * 32 + lrow * 8);
        #pragma unroll
        for (int ni = 0; ni < 4; ++ni)
            bfr[ni] = ld_frag(&Bs[cur][0] + (wn * 64 + ni * 16 + lcol) * 32 + lrow * 8);
        #pragma unroll
        for (int mi = 0; mi < 4; ++mi)
            #pragma unroll
            for (int ni = 0; ni < 4; ++ni)
                acc[mi][ni] = __builtin_amdgcn_mfma_f32_16x16x32_bf16(af[mi], bfr[ni], acc[mi][ni], 0, 0, 0);

        __syncthreads();
        cur ^= 1;
    }

    #pragma unroll
    for (int mi = 0; mi < 4; ++mi) {
        int gr0 = tm0 + wm * 64 + mi * 16 + lrow * 4;
        #pragma unroll
        for (int ni = 0; ni < 4; ++ni) {
            int gc = tn0 + wn * 64 + ni * 16 + lcol;
            float bv = bias[gc];
            if (MODE == 0) {
                int sec = gc >> 10, ei = gc & 1023;
                unsigned short* dst = sec == 0 ? qb : (sec == 1 ? kb : vb);
                if (sec == 0) {
                    #pragma unroll
                    for (int r = 0; r < 4; ++r)
                        dst[(long)(gr0 + r) * 1024 + ei] = f2bf((acc[mi][ni][r] + bv) * QSCALE);
                } else {
                    #pragma unroll
                    for (int r = 0; r < 4; ++r)
                        dst[(long)(gr0 + r) * 1024 + ei] = f2bf(acc[mi][ni][r] + bv);
                }
            } else {
                #pragma unroll
                for (int r = 0; r < 4; ++r)
                    outf[(long)(gr0 + r) * 1024 + gc] = acc[mi][ni][r] + bv;
            }
        }
    }
}

// ---------------- flash attention: shared-LDS K/V walk, 4 waves x 32 q-rows ----------------
// Block (bh, panel j): q rows [j*128, j*128+128), wave w owns rows j*128+w*32..+32.
// All waves walk K-tiles of 64 keys staged in LDS (double-buffered, counted vmcnt(4)).
// XOR swizzle: LDS[r][slot s] holds source granule s^(r&7); readers use slot g^(r&7).
__global__ __launch_bounds__(256) void attn(
    const unsigned short* __restrict__ qbuf,
    const unsigned short* __restrict__ kbuf,
    const unsigned short* __restrict__ vtbuf,
    unsigned short* __restrict__ obuf)
{
    __shared__ unsigned short Ks[2][4096];   // [64 k][64 d], rows = 128B, swizzled
    __shared__ unsigned short Vs[2][4096];   // [64 d][64 k], rows = 128B, swizzled
    __shared__ unsigned short Ps[4][32][40]; // per-wave P

    int id = blockIdx.x;
    int xcd = id & 7, s_ = id >> 3;
    int j  = 7 - (s_ >> 3);                  // panels descending (LPT: long first)
    int bh = xcd + 8 * (s_ & 7);             // bh pinned to XCD

    const char* Kb = (const char*)(kbuf + (long)bh * 65536);
    const char* Vb = (const char*)(vtbuf + (long)bh * 65536);
    const unsigned short* Q = qbuf + (long)bh * 65536;
    unsigned short* O = obuf + (long)bh * 65536;

    int t = threadIdx.x, lane = t & 63, w = t >> 6;
    int lrow = lane >> 4, lcol = lane & 15;
    const float NEG = -__builtin_inff();

    int qbase = j * 128 + w * 32;            // wave's 32 q-rows
    int T = 2 * j + 2;                       // 64-key tiles for this panel

    // staging geometry: per call, wave covers 8 rows (1KB); slot swizzle is lane-constant
    int row0 = w * 8 + (lane >> 3);
    int slot = (((lane & 7) ^ (lane >> 3)) << 4);

    auto STAGE = [&](int buf, int kt) {
        long k2 = (long)kt * 2;
        gload_lds16(Kb + (k2 + row0 * 2) * 64 + slot,        (char*)&Ks[buf][0] + w * 1024);
        gload_lds16(Kb + (k2 + (row0 + 32) * 2) * 64 + slot, (char*)&Ks[buf][0] + 4096 + w * 1024);
        gload_lds16(Vb + (long)row0 * 2048 + k2 + slot,        (char*)&Vs[buf][0] + w * 1024);
        gload_lds16(Vb + (long)(row0 + 32) * 2048 + k2 + slot, (char*)&Vs[buf][0] + 4096 + w * 1024);
    };

    // Q fragments (global, once)
    bf16x8 qf[2][2];
    #pragma unroll
    for (int qg = 0; qg < 2; ++qg)
        #pragma unroll
        for (int kc = 0; kc < 2; ++kc)
            qf[qg][kc] = ld_frag(Q + (long)(qbase + qg * 16 + lcol) * 64 + kc * 32 + lrow * 8);

    f32x4 acc[2][4] = {};
    float m_i[2] = {NEG, NEG};
    float lsum[2][2] = {{0.f, 0.f}, {0.f, 0.f}};

    STAGE(0, 0);
    STAGE(1, 64);

    for (int tt = 0; tt < T; ++tt) {
        if (tt + 1 < T) asm volatile("s_waitcnt vmcnt(4)" ::: "memory");
        else            asm volatile("s_waitcnt vmcnt(0)" ::: "memory");
        __builtin_amdgcn_s_barrier();          // tile tt landed for all waves

        int cur = tt & 1;
        #pragma unroll
        for (int ks = 0; ks < 2; ++ks) {
            int kt_sub = tt * 64 + ks * 32;
            if (kt_sub <= qbase) {
                // --- fragments from LDS (swizzled) ---
                bf16x8 kf[2][2], vf[4];
                #pragma unroll
                for (int kg = 0; kg < 2; ++kg)
                    #pragma unroll
                    for (int kc = 0; kc < 2; ++kc) {
                        int row = ks * 32 + kg * 16 + lcol;
                        kf[kg][kc] = ld_frag(&Ks[cur][row * 64 + (((kc * 4 + lrow) ^ (row & 7)) << 3)]);
                    }
                #pragma unroll
                for (int dg = 0; dg < 4; ++dg) {
                    int row = dg * 16 + lcol;
                    vf[dg] = ld_frag(&Vs[cur][row * 64 + (((ks * 4 + lrow) ^ (row & 7)) << 3)]);
                }

                // --- S^T = K * Qs ---
                f32x4 s[2][2] = {};
                __builtin_amdgcn_s_setprio(1);
                #pragma unroll
                for (int kg = 0; kg < 2; ++kg)
                    #pragma unroll
                    for (int kc = 0; kc < 2; ++kc) {
                        s[0][kg] = __builtin_amdgcn_mfma_f32_16x16x32_bf16(kf[kg][kc], qf[0][kc], s[0][kg], 0, 0, 0);
                        s[1][kg] = __builtin_amdgcn_mfma_f32_16x16x32_bf16(kf[kg][kc], qf[1][kc], s[1][kg], 0, 0, 0);
                    }
                __builtin_amdgcn_s_setprio(0);

                // --- softmax (diag-only masking, defer-max, exp2) ---
                bool diag = (kt_sub == qbase);
                if (diag) {
                    #pragma unroll
                    for (int qg = 0; qg < 2; ++qg)
                        #pragma unroll
                        for (int kg = 0; kg < 2; ++kg)
                            #pragma unroll
                            for (int r = 0; r < 4; ++r)
                                if (kg * 16 + lrow * 4 + r > qg * 16 + lcol)
                                    s[qg][kg][r] = NEG;
                }
                float lmax[2];
                #pragma unroll
                for (int qg = 0; qg < 2; ++qg) {
                    float a0 = fmaxf(s[qg][0][0], s[qg][0][1]), a1 = fmaxf(s[qg][0][2], s[qg][0][3]);
                    float a2 = fmaxf(s[qg][1][0], s[qg][1][1]), a3 = fmaxf(s[qg][1][2], s[qg][1][3]);
                    lmax[qg] = fmaxf(fmaxf(a0, a1), fmaxf(a2, a3));
                }
                bool ok = (lmax[0] <= m_i[0] + DEFER_THR) && (lmax[1] <= m_i[1] + DEFER_THR);
                if (!__all(ok)) {
                    #pragma unroll
                    for (int qg = 0; qg < 2; ++qg) {
                        float mx = fmaxf(lmax[qg], __shfl_xor(lmax[qg], 16));
                        mx = fmaxf(mx, __shfl_xor(mx, 32));
                        float mnew = fmaxf(m_i[qg], mx);
                        float alpha = exp2f(m_i[qg] - mnew);
                        m_i[qg] = mnew;
                        lsum[qg][0] *= alpha;
                        lsum[qg][1] *= alpha;
                        #pragma unroll
                        for (int dg = 0; dg < 4; ++dg)
                            #pragma unroll
                            for (int r = 0; r < 4; ++r)
                                acc[qg][dg][r] *= alpha;
                    }
                }
                #pragma unroll
                for (int qg = 0; qg < 2; ++qg) {
                    float p[8];
                    #pragma unroll
                    for (int kg = 0; kg < 2; ++kg)
                        #pragma unroll
                        for (int r = 0; r < 4; ++r)
                            p[kg * 4 + r] = exp2f(s[qg][kg][r] - m_i[qg]);
                    lsum[qg][0] += (p[0] + p[1]) + (p[2] + p[3]);
                    lsum[qg][1] += (p[4] + p[5]) + (p[6] + p[7]);
                    unsigned u0 = cvtpk_bf16(p[0], p[1]);
                    unsigned u1 = cvtpk_bf16(p[2], p[3]);
                    unsigned u2 = cvtpk_bf16(p[4], p[5]);
                    unsigned u3 = cvtpk_bf16(p[6], p[7]);
                    *(uint2*)&Ps[w][qg * 16 + lcol][lrow * 4]      = make_uint2(u0, u1);
                    *(uint2*)&Ps[w][qg * 16 + lcol][16 + lrow * 4] = make_uint2(u2, u3);
                }

                bf16x8 pb[2];
                pb[0] = ld_frag(&Ps[w][lcol][lrow * 8]);
                pb[1] = ld_frag(&Ps[w][16 + lcol][lrow * 8]);

                // --- O^T += V^T * P ---
                __builtin_amdgcn_s_setprio(1);
                #pragma unroll
                for (int dg = 0; dg < 4; ++dg) {
                    acc[0][dg] = __builtin_amdgcn_mfma_f32_16x16x32_bf16(vf[dg], pb[0], acc[0][dg], 0, 0, 0);
                    acc[1][dg] = __builtin_amdgcn_mfma_f32_16x16x32_bf16(vf[dg], pb[1], acc[1][dg], 0, 0, 0);
                }
                __builtin_amdgcn_s_setprio(0);
            }
        }

        __builtin_amdgcn_s_barrier();          // all reads of buf[cur] done
        if (tt + 2 < T) STAGE(cur, (tt + 2) * 64);
    }

    // --- epilogue: O = acc / l (no merge — wave owns its rows) ---
    #pragma unroll
    for (int qg = 0; qg < 2; ++qg) {
        float lr = lsum[qg][0] + lsum[qg][1];
        lr += __shfl_xor(lr, 16);
        lr += __shfl_xor(lr, 32);
        float inv = 1.f / lr;
        int q = qbase + qg * 16 + lcol;
        #pragma unroll
        for (int dg = 0; dg < 4; ++dg) {
            ushort4 pk;
            pk.x = f2bf(acc[qg][dg][0] * inv);
            pk.y = f2bf(acc[qg][dg][1] * inv);
            pk.z = f2bf(acc[qg][dg][2] * inv);
            pk.w = f2bf(acc[qg][dg][3] * inv);
            *(ushort4*)&O[(long)q * 64 + dg * 16 + lrow * 4] = pk;
        }
    }
}

extern "C" void kernel_launch(void* const* d_in, const int* in_sizes, int n_in,
                              void* d_out, int out_size, void* d_ws, size_t ws_size,
                              hipStream_t stream) {
    const float* x    = (const float*)d_in[0];
    const float* Wqkv = (const float*)d_in[1];
    const float* bqkv = (const float*)d_in[2];
    const float* Wfc  = (const float*)d_in[3];
    const float* bfc  = (const float*)d_in[4];
    float* out = (float*)d_out;

    unsigned short* ws    = (unsigned short*)d_ws;
    unsigned short* xb    = ws;                    // 4M elems; dead after gemm<0>
    unsigned short* wqkvT = xb + (4u << 20);       // 3M
    unsigned short* wfcT  = wqkvT + (3u << 20);    // 1M
    unsigned short* qb    = wfcT + (1u << 20);     // 4M
    unsigned short* kb    = qb + (4u << 20);       // 4M
    unsigned short* vb    = kb + (4u << 20);       // 4M; dead after transpose_v
    unsigned short* vbT   = xb;                    // reuse xb
    unsigned short* ob    = vb;                    // reuse vb
    // total ws: 40 MB

    prep<<<dim3(5120), dim3(256), 0, stream>>>(x, xb, Wqkv, wqkvT, Wfc, wfcT);
    gemm128<0><<<dim3(768), dim3(256), 0, stream>>>(xb, wqkvT, bqkv, qb, kb, vb, nullptr);
    transpose_v<<<dim3(32, 2, 64), dim3(32, 8), 0, stream>>>(vb, vbT);
    attn<<<dim3(512), dim3(256), 0, stream>>>(qb, kb, vbT, ob);
    gemm128<1><<<dim3(256), dim3(256), 0, stream>>>(ob, wfcT, bfc, nullptr, nullptr, nullptr, out);
}